// Round 1
// baseline (886.398 us; speedup 1.0000x reference)
//
#include <hip/hip_runtime.h>

#define N_NODES 50000
#define N_EDGES 800000
#define FDIM 128
#define NROWS 100000   // B * N_NODES
#define BN_EPS 1e-5f

// ---------------- CSR build (per-destination buckets) ----------------

__global__ __launch_bounds__(256) void hist_kernel(const int* __restrict__ col,
                                                   int* __restrict__ cnt) {
    int e = blockIdx.x * 256 + threadIdx.x;
    if (e < N_EDGES) atomicAdd(&cnt[col[e]], 1);
}

// Single-block exclusive scan over 50000 counts -> offsets[50001]; also copies to cursor.
__global__ __launch_bounds__(256) void scan_kernel(const int* __restrict__ cnt,
                                                   int* __restrict__ offsets,
                                                   int* __restrict__ cursor) {
    __shared__ int wsum[4];
    __shared__ int s_carry;
    int tid = threadIdx.x, lane = tid & 63, wid = tid >> 6;
    if (tid == 0) s_carry = 0;
    __syncthreads();
    for (int base = 0; base < N_NODES; base += 256) {
        int i = base + tid;
        int v = (i < N_NODES) ? cnt[i] : 0;
        int x = v;
        #pragma unroll
        for (int d = 1; d < 64; d <<= 1) {
            int y = __shfl_up(x, d);
            if (lane >= d) x += y;
        }
        if (lane == 63) wsum[wid] = x;
        __syncthreads();
        int woff = 0;
        for (int w = 0; w < wid; ++w) woff += wsum[w];
        int carry = s_carry;
        if (i < N_NODES) {
            int excl = carry + woff + x - v;
            offsets[i] = excl;
            cursor[i] = excl;
        }
        __syncthreads();
        if (tid == 255) s_carry = carry + woff + x;
    }
    __syncthreads();
    if (tid == 0) offsets[N_NODES] = s_carry;
}

__global__ __launch_bounds__(256) void bucket_kernel(const int* __restrict__ row,
                                                     const int* __restrict__ col,
                                                     int* __restrict__ cursor,
                                                     int* __restrict__ srcbuf) {
    int e = blockIdx.x * 256 + threadIdx.x;
    if (e < N_EDGES) {
        int c = col[e];
        int p = atomicAdd(&cursor[c], 1);
        srcbuf[p] = row[e];
    }
}

// ---------------- GEMM: C[100000,128] = A[100000,128] @ W[128,128] (fp32) ----------------
// 64-row tile in LDS (XOR-swizzled to kill bank conflicts on row-broadcast reads),
// W staged in two 64-column halves (sA 32KB + sW 32KB = 64KB LDS -> 2 blocks/CU).
__global__ __launch_bounds__(256) void gemm128(const float* __restrict__ A,
                                               const float* __restrict__ Wm,
                                               float* __restrict__ C) {
    __shared__ float sA[64 * 128];
    __shared__ float sW[128 * 64];
    int tid = threadIdx.x;
    long r0 = (long)blockIdx.x * 64;
    const float4* A4 = (const float4*)A;
    const float4* W4 = (const float4*)Wm;
    float4* sA4 = (float4*)sA;
    float4* sW4 = (float4*)sW;

    #pragma unroll
    for (int i = 0; i < 8; ++i) {
        int li = tid + i * 256;          // 0..2047
        int r = li >> 5, kc = li & 31;   // row 0..63, k-chunk 0..31
        long gr = r0 + r;
        float4 v = make_float4(0.f, 0.f, 0.f, 0.f);
        if (gr < NROWS) v = A4[gr * 32 + kc];
        sA4[r * 32 + (kc ^ (r & 31))] = v;
    }

    int tc = tid & 15;   // 16 col-groups of 4 cols (within a 64-col half)
    int tr = tid >> 4;   // 16 row-groups of 4 rows
    float4* C4 = (float4*)C;

    for (int half = 0; half < 2; ++half) {
        __syncthreads();
        #pragma unroll
        for (int i = 0; i < 8; ++i) {
            int li = tid + i * 256;        // 0..2047
            int k = li >> 4, c4 = li & 15;
            sW4[li] = W4[k * 32 + half * 16 + c4];
        }
        __syncthreads();

        float acc[4][4] = {};
        #pragma unroll 2
        for (int kc = 0; kc < 32; ++kc) {
            float4 a0 = sA4[(tr * 4 + 0) * 32 + (kc ^ ((tr * 4 + 0) & 31))];
            float4 a1 = sA4[(tr * 4 + 1) * 32 + (kc ^ ((tr * 4 + 1) & 31))];
            float4 a2 = sA4[(tr * 4 + 2) * 32 + (kc ^ ((tr * 4 + 2) & 31))];
            float4 a3 = sA4[(tr * 4 + 3) * 32 + (kc ^ ((tr * 4 + 3) & 31))];
            float4 w0 = sW4[(kc * 4 + 0) * 16 + tc];
            float4 w1 = sW4[(kc * 4 + 1) * 16 + tc];
            float4 w2 = sW4[(kc * 4 + 2) * 16 + tc];
            float4 w3 = sW4[(kc * 4 + 3) * 16 + tc];
            #define GROW(r, a)                                             \
                acc[r][0] += a.x * w0.x + a.y * w1.x + a.z * w2.x + a.w * w3.x; \
                acc[r][1] += a.x * w0.y + a.y * w1.y + a.z * w2.y + a.w * w3.y; \
                acc[r][2] += a.x * w0.z + a.y * w1.z + a.z * w2.z + a.w * w3.z; \
                acc[r][3] += a.x * w0.w + a.y * w1.w + a.z * w2.w + a.w * w3.w;
            GROW(0, a0) GROW(1, a1) GROW(2, a2) GROW(3, a3)
            #undef GROW
        }

        #pragma unroll
        for (int r = 0; r < 4; ++r) {
            long gr = r0 + tr * 4 + r;
            if (gr < NROWS)
                C4[gr * 32 + half * 16 + tc] =
                    make_float4(acc[r][0], acc[r][1], acc[r][2], acc[r][3]);
        }
    }
}

// ---------------- Aggregate: agg[b,n,:] = sum over CSR in-edges of sup[b,src,:] ----------------
// One wave per (batch, node); lane holds 2 columns (float2) -> 512B coalesced row gather.
__global__ __launch_bounds__(256) void aggregate_kernel(const float* __restrict__ sup,
                                                        const int* __restrict__ offsets,
                                                        const int* __restrict__ srcbuf,
                                                        float* __restrict__ agg) {
    int lane = threadIdx.x & 63;
    int wid = threadIdx.x >> 6;
    int gw = blockIdx.x * 4 + wid;
    if (gw >= 2 * N_NODES) return;
    int b = (gw >= N_NODES) ? 1 : 0;
    int node = gw - b * N_NODES;
    int beg = offsets[node], end = offsets[node + 1];
    const float2* supb = (const float2*)(sup + (size_t)b * N_NODES * FDIM);
    float2 acc = make_float2(0.f, 0.f);
    for (int i = beg; i < end; i += 64) {
        int m = end - i; if (m > 64) m = 64;
        int idx = (i + lane < end) ? srcbuf[i + lane] : 0;  // coalesced index load
        for (int j = 0; j < m; ++j) {
            int r = __shfl(idx, j);
            float2 v = supb[(size_t)r * 64 + lane];
            acc.x += v.x; acc.y += v.y;
        }
    }
    ((float2*)agg)[(size_t)gw * 64 + lane] = acc;
}

// ---------------- BatchNorm (training-mode batch stats) ----------------

__global__ __launch_bounds__(256) void bn_stats_kernel(const float* __restrict__ h,
                                                       float* __restrict__ stats) {
    __shared__ float ls[256], ls2[256];
    int tid = threadIdx.x;
    int f = tid & 127, half = tid >> 7;
    float s = 0.f, s2 = 0.f;
    for (int row = blockIdx.x * 2 + half; row < NROWS; row += gridDim.x * 2) {
        float v = h[(size_t)row * FDIM + f];
        s += v; s2 += v * v;
    }
    ls[tid] = s; ls2[tid] = s2;
    __syncthreads();
    if (tid < 128) {
        atomicAdd(&stats[f], ls[tid] + ls[tid + 128]);
        atomicAdd(&stats[128 + f], ls2[tid] + ls2[tid + 128]);
    }
}

__global__ void bn_coef_kernel(const float* __restrict__ stats,
                               const float* __restrict__ gamma,
                               const float* __restrict__ beta,
                               float* __restrict__ coef) {
    int f = threadIdx.x;
    if (f < 128) {
        float inv = 1.0f / (float)NROWS;
        float mean = stats[f] * inv;
        float var = stats[128 + f] * inv - mean * mean;  // biased var, matches jnp.var
        float scale = gamma[f] / sqrtf(var + BN_EPS);
        coef[f] = scale;
        coef[128 + f] = beta[f] - mean * scale;
    }
}

// h = relu(h * scale[f] + shift[f]), in place, float4-vectorized (3.2M float4s)
__global__ __launch_bounds__(256) void bn_relu_kernel(float* __restrict__ h,
                                                      const float* __restrict__ coef) {
    int i = blockIdx.x * 256 + threadIdx.x;     // exact: 12500*256 = 3,200,000
    const float4* coef4 = (const float4*)coef;
    float4 sc = coef4[i & 31];
    float4 sh = coef4[32 + (i & 31)];
    float4* h4 = (float4*)h;
    float4 v = h4[i];
    v.x = fmaxf(v.x * sc.x + sh.x, 0.f);
    v.y = fmaxf(v.y * sc.y + sh.y, 0.f);
    v.z = fmaxf(v.z * sc.z + sh.z, 0.f);
    v.w = fmaxf(v.w * sc.w + sh.w, 0.f);
    h4[i] = v;
}

// ---------------- Layer 3: GEMV + scalar scatter ----------------

__global__ __launch_bounds__(256) void gemv_kernel(const float* __restrict__ h,
                                                   const float* __restrict__ W3,
                                                   float* __restrict__ sup3) {
    int lane = threadIdx.x & 63, wid = threadIdx.x >> 6;
    int gw = blockIdx.x * 4 + wid;
    if (gw >= NROWS) return;
    float2 w = ((const float2*)W3)[lane];
    float2 v = ((const float2*)h)[(size_t)gw * 64 + lane];
    float s = v.x * w.x + v.y * w.y;
    #pragma unroll
    for (int d = 32; d > 0; d >>= 1) s += __shfl_xor(s, d);
    if (lane == 0) sup3[gw] = s;
}

__global__ void out_init_kernel(float* __restrict__ out, const float* __restrict__ b3) {
    int i = blockIdx.x * 256 + threadIdx.x;
    if (i < NROWS) out[i] = b3[0];
}

__global__ __launch_bounds__(256) void scatter_out_kernel(const int* __restrict__ row,
                                                          const int* __restrict__ col,
                                                          const float* __restrict__ sup3,
                                                          float* __restrict__ out) {
    int e = blockIdx.x * 256 + threadIdx.x;
    if (e < N_EDGES) {
        int r = row[e], c = col[e];
        atomicAdd(&out[c], sup3[r]);
        atomicAdd(&out[N_NODES + c], sup3[N_NODES + r]);
    }
}

// ---------------- launch ----------------

extern "C" void kernel_launch(void* const* d_in, const int* in_sizes, int n_in,
                              void* d_out, int out_size, void* d_ws, size_t ws_size,
                              hipStream_t stream) {
    const float* x      = (const float*)d_in[0];
    const int*   ei     = (const int*)d_in[1];
    const float* W1     = (const float*)d_in[2];
    // d_in[3] = b1: per-feature bias before BN cancels exactly (shifts mean identically)
    const float* W2     = (const float*)d_in[4];
    // d_in[5] = b2: same cancellation
    const float* W3     = (const float*)d_in[6];
    const float* b3     = (const float*)d_in[7];
    const float* gamma1 = (const float*)d_in[8];
    const float* beta1  = (const float*)d_in[9];
    const float* gamma2 = (const float*)d_in[10];
    const float* beta2  = (const float*)d_in[11];
    const int* rowp = ei;             // edge_index[0]
    const int* colp = ei + N_EDGES;   // edge_index[1]

    float* sup     = (float*)d_ws;           // 12.8M floats (51.2 MB)
    float* agg     = sup + 12800000;         // 12.8M floats (51.2 MB)
    float* sup3    = agg + 12800000;         // 100k floats
    float* stats   = sup3 + 100000;          // 512 floats (layer1: [0..255], layer2: [256..511])
    float* coef    = stats + 512;            // 512 floats
    int*   cnt     = (int*)(coef + 512);     // 50000
    int*   offsets = cnt + N_NODES;          // 50001
    int*   cursor  = offsets + N_NODES + 1;  // 50000
    int*   srcbuf  = cursor + N_NODES;       // 800000
    float* out     = (float*)d_out;

    hipMemsetAsync(cnt, 0, N_NODES * sizeof(int), stream);
    hipMemsetAsync(stats, 0, 512 * sizeof(float), stream);

    // CSR build (edge_index identical for both batches and all layers)
    hist_kernel  <<<3125, 256, 0, stream>>>(colp, cnt);
    scan_kernel  <<<1,    256, 0, stream>>>(cnt, offsets, cursor);
    bucket_kernel<<<3125, 256, 0, stream>>>(rowp, colp, cursor, srcbuf);

    // layer 1
    gemm128         <<<1563,  256, 0, stream>>>(x, W1, sup);
    aggregate_kernel<<<25000, 256, 0, stream>>>(sup, offsets, srcbuf, agg);
    bn_stats_kernel <<<512,   256, 0, stream>>>(agg, stats);
    bn_coef_kernel  <<<1,     128, 0, stream>>>(stats, gamma1, beta1, coef);
    bn_relu_kernel  <<<12500, 256, 0, stream>>>(agg, coef);

    // layer 2
    gemm128         <<<1563,  256, 0, stream>>>(agg, W2, sup);
    aggregate_kernel<<<25000, 256, 0, stream>>>(sup, offsets, srcbuf, agg);
    bn_stats_kernel <<<512,   256, 0, stream>>>(agg, stats + 256);
    bn_coef_kernel  <<<1,     128, 0, stream>>>(stats + 256, gamma2, beta2, coef + 256);
    bn_relu_kernel  <<<12500, 256, 0, stream>>>(agg, coef + 256);

    // layer 3 (output dim 1)
    gemv_kernel       <<<25000, 256, 0, stream>>>(agg, W3, sup3);
    out_init_kernel   <<<391,   256, 0, stream>>>(out, b3);
    scatter_out_kernel<<<3125,  256, 0, stream>>>(rowp, colp, sup3, out);
}

// Round 2
// 762.677 us; speedup vs baseline: 1.1622x; 1.1622x over previous
//
#include <hip/hip_runtime.h>

#define N_NODES 50000
#define N_EDGES 800000
#define FDIM 128
#define NROWS 100000   // B * N_NODES
#define BN_EPS 1e-5f
#define SCAN_BLOCKS 196   // ceil(50000 / 256)

// ---------------- CSR build (per-destination buckets) ----------------

__global__ __launch_bounds__(256) void hist_kernel(const int* __restrict__ col,
                                                   int* __restrict__ cnt) {
    int e = blockIdx.x * 256 + threadIdx.x;
    if (e < N_EDGES) atomicAdd(&cnt[col[e]], 1);
}

// Phase 1: per-block sums of 256-count chunks.
__global__ __launch_bounds__(256) void scan_partials_sum(const int* __restrict__ cnt,
                                                         int* __restrict__ partials) {
    __shared__ int ws[4];
    int tid = threadIdx.x, lane = tid & 63, wid = tid >> 6;
    int i = blockIdx.x * 256 + tid;
    int v = (i < N_NODES) ? cnt[i] : 0;
    #pragma unroll
    for (int d = 32; d > 0; d >>= 1) v += __shfl_xor(v, d);
    if (lane == 0) ws[wid] = v;
    __syncthreads();
    if (tid == 0) partials[blockIdx.x] = ws[0] + ws[1] + ws[2] + ws[3];
}

// Phase 2: single block exclusive-scans the 196 partials in place.
__global__ __launch_bounds__(256) void scan_partials_scan(int* __restrict__ partials,
                                                          int* __restrict__ offsets) {
    __shared__ int ws[4];
    int tid = threadIdx.x, lane = tid & 63, wid = tid >> 6;
    int v = (tid < SCAN_BLOCKS) ? partials[tid] : 0;
    int x = v;
    #pragma unroll
    for (int d = 1; d < 64; d <<= 1) {
        int y = __shfl_up(x, d);
        if (lane >= d) x += y;
    }
    if (lane == 63) ws[wid] = x;
    __syncthreads();
    int woff = 0;
    for (int w = 0; w < wid; ++w) woff += ws[w];
    if (tid < SCAN_BLOCKS) partials[tid] = woff + x - v;   // exclusive
    if (tid == 255) offsets[N_NODES] = woff + x;           // grand total
}

// Phase 3: block-local exclusive scan + partial offset -> offsets, cursor.
__global__ __launch_bounds__(256) void scan_final(const int* __restrict__ cnt,
                                                  const int* __restrict__ partials,
                                                  int* __restrict__ offsets,
                                                  int* __restrict__ cursor) {
    __shared__ int ws[4];
    int tid = threadIdx.x, lane = tid & 63, wid = tid >> 6;
    int i = blockIdx.x * 256 + tid;
    int v = (i < N_NODES) ? cnt[i] : 0;
    int x = v;
    #pragma unroll
    for (int d = 1; d < 64; d <<= 1) {
        int y = __shfl_up(x, d);
        if (lane >= d) x += y;
    }
    if (lane == 63) ws[wid] = x;
    __syncthreads();
    int woff = 0;
    for (int w = 0; w < wid; ++w) woff += ws[w];
    if (i < N_NODES) {
        int off = partials[blockIdx.x] + woff + x - v;
        offsets[i] = off;
        cursor[i] = off;
    }
}

__global__ __launch_bounds__(256) void bucket_kernel(const int* __restrict__ row,
                                                     const int* __restrict__ col,
                                                     int* __restrict__ cursor,
                                                     int* __restrict__ srcbuf) {
    int e = blockIdx.x * 256 + threadIdx.x;
    if (e < N_EDGES) {
        int c = col[e];
        int p = atomicAdd(&cursor[c], 1);
        srcbuf[p] = row[e];
    }
}

// ---------------- GEMM: C[100000,128] = A[100000,128] @ W[128,128] (fp32) ----------------
__global__ __launch_bounds__(256) void gemm128(const float* __restrict__ A,
                                               const float* __restrict__ Wm,
                                               float* __restrict__ C) {
    __shared__ float sA[64 * 128];
    __shared__ float sW[128 * 64];
    int tid = threadIdx.x;
    long r0 = (long)blockIdx.x * 64;
    const float4* A4 = (const float4*)A;
    const float4* W4 = (const float4*)Wm;
    float4* sA4 = (float4*)sA;
    float4* sW4 = (float4*)sW;

    #pragma unroll
    for (int i = 0; i < 8; ++i) {
        int li = tid + i * 256;          // 0..2047
        int r = li >> 5, kc = li & 31;   // row 0..63, k-chunk 0..31
        long gr = r0 + r;
        float4 v = make_float4(0.f, 0.f, 0.f, 0.f);
        if (gr < NROWS) v = A4[gr * 32 + kc];
        sA4[r * 32 + (kc ^ (r & 31))] = v;
    }

    int tc = tid & 15;   // 16 col-groups of 4 cols (within a 64-col half)
    int tr = tid >> 4;   // 16 row-groups of 4 rows
    float4* C4 = (float4*)C;

    for (int half = 0; half < 2; ++half) {
        __syncthreads();
        #pragma unroll
        for (int i = 0; i < 8; ++i) {
            int li = tid + i * 256;        // 0..2047
            int k = li >> 4, c4 = li & 15;
            sW4[li] = W4[k * 32 + half * 16 + c4];
        }
        __syncthreads();

        float acc[4][4] = {};
        #pragma unroll 2
        for (int kc = 0; kc < 32; ++kc) {
            float4 a0 = sA4[(tr * 4 + 0) * 32 + (kc ^ ((tr * 4 + 0) & 31))];
            float4 a1 = sA4[(tr * 4 + 1) * 32 + (kc ^ ((tr * 4 + 1) & 31))];
            float4 a2 = sA4[(tr * 4 + 2) * 32 + (kc ^ ((tr * 4 + 2) & 31))];
            float4 a3 = sA4[(tr * 4 + 3) * 32 + (kc ^ ((tr * 4 + 3) & 31))];
            float4 w0 = sW4[(kc * 4 + 0) * 16 + tc];
            float4 w1 = sW4[(kc * 4 + 1) * 16 + tc];
            float4 w2 = sW4[(kc * 4 + 2) * 16 + tc];
            float4 w3 = sW4[(kc * 4 + 3) * 16 + tc];
            #define GROW(r, a)                                             \
                acc[r][0] += a.x * w0.x + a.y * w1.x + a.z * w2.x + a.w * w3.x; \
                acc[r][1] += a.x * w0.y + a.y * w1.y + a.z * w2.y + a.w * w3.y; \
                acc[r][2] += a.x * w0.z + a.y * w1.z + a.z * w2.z + a.w * w3.z; \
                acc[r][3] += a.x * w0.w + a.y * w1.w + a.z * w2.w + a.w * w3.w;
            GROW(0, a0) GROW(1, a1) GROW(2, a2) GROW(3, a3)
            #undef GROW
        }

        #pragma unroll
        for (int r = 0; r < 4; ++r) {
            long gr = r0 + tr * 4 + r;
            if (gr < NROWS)
                C4[gr * 32 + half * 16 + tc] =
                    make_float4(acc[r][0], acc[r][1], acc[r][2], acc[r][3]);
        }
    }
}

// ---------------- Aggregate: agg[b,n,:] = sum over CSR in-edges of sup[b,src,:] ----------------
__global__ __launch_bounds__(256) void aggregate_kernel(const float* __restrict__ sup,
                                                        const int* __restrict__ offsets,
                                                        const int* __restrict__ srcbuf,
                                                        float* __restrict__ agg) {
    int lane = threadIdx.x & 63;
    int wid = threadIdx.x >> 6;
    int gw = blockIdx.x * 4 + wid;
    if (gw >= 2 * N_NODES) return;
    int b = (gw >= N_NODES) ? 1 : 0;
    int node = gw - b * N_NODES;
    int beg = offsets[node], end = offsets[node + 1];
    const float2* supb = (const float2*)(sup + (size_t)b * N_NODES * FDIM);
    float2 acc = make_float2(0.f, 0.f);
    for (int i = beg; i < end; i += 64) {
        int m = end - i; if (m > 64) m = 64;
        int idx = (i + lane < end) ? srcbuf[i + lane] : 0;  // coalesced index load
        for (int j = 0; j < m; ++j) {
            int r = __shfl(idx, j);
            float2 v = supb[(size_t)r * 64 + lane];
            acc.x += v.x; acc.y += v.y;
        }
    }
    ((float2*)agg)[(size_t)gw * 64 + lane] = acc;
}

// ---------------- BatchNorm (training-mode batch stats) ----------------

__global__ __launch_bounds__(256) void bn_stats_kernel(const float* __restrict__ h,
                                                       float* __restrict__ stats) {
    __shared__ float ls[256], ls2[256];
    int tid = threadIdx.x;
    int f = tid & 127, half = tid >> 7;
    float s = 0.f, s2 = 0.f;
    for (int row = blockIdx.x * 2 + half; row < NROWS; row += gridDim.x * 2) {
        float v = h[(size_t)row * FDIM + f];
        s += v; s2 += v * v;
    }
    ls[tid] = s; ls2[tid] = s2;
    __syncthreads();
    if (tid < 128) {
        atomicAdd(&stats[f], ls[tid] + ls[tid + 128]);
        atomicAdd(&stats[128 + f], ls2[tid] + ls2[tid + 128]);
    }
}

__global__ void bn_coef_kernel(const float* __restrict__ stats,
                               const float* __restrict__ gamma,
                               const float* __restrict__ beta,
                               float* __restrict__ coef) {
    int f = threadIdx.x;
    if (f < 128) {
        float inv = 1.0f / (float)NROWS;
        float mean = stats[f] * inv;
        float var = stats[128 + f] * inv - mean * mean;  // biased var, matches jnp.var
        float scale = gamma[f] / sqrtf(var + BN_EPS);
        coef[f] = scale;
        coef[128 + f] = beta[f] - mean * scale;
    }
}

__global__ __launch_bounds__(256) void bn_relu_kernel(float* __restrict__ h,
                                                      const float* __restrict__ coef) {
    int i = blockIdx.x * 256 + threadIdx.x;     // exact: 12500*256 = 3,200,000
    const float4* coef4 = (const float4*)coef;
    float4 sc = coef4[i & 31];
    float4 sh = coef4[32 + (i & 31)];
    float4* h4 = (float4*)h;
    float4 v = h4[i];
    v.x = fmaxf(v.x * sc.x + sh.x, 0.f);
    v.y = fmaxf(v.y * sc.y + sh.y, 0.f);
    v.z = fmaxf(v.z * sc.z + sh.z, 0.f);
    v.w = fmaxf(v.w * sc.w + sh.w, 0.f);
    h4[i] = v;
}

// ---------------- Layer 3: GEMV + scalar scatter ----------------

__global__ __launch_bounds__(256) void gemv_kernel(const float* __restrict__ h,
                                                   const float* __restrict__ W3,
                                                   float* __restrict__ sup3) {
    int lane = threadIdx.x & 63, wid = threadIdx.x >> 6;
    int gw = blockIdx.x * 4 + wid;
    if (gw >= NROWS) return;
    float2 w = ((const float2*)W3)[lane];
    float2 v = ((const float2*)h)[(size_t)gw * 64 + lane];
    float s = v.x * w.x + v.y * w.y;
    #pragma unroll
    for (int d = 32; d > 0; d >>= 1) s += __shfl_xor(s, d);
    if (lane == 0) sup3[gw] = s;
}

__global__ void out_init_kernel(float* __restrict__ out, const float* __restrict__ b3) {
    int i = blockIdx.x * 256 + threadIdx.x;
    if (i < NROWS) out[i] = b3[0];
}

__global__ __launch_bounds__(256) void scatter_out_kernel(const int* __restrict__ row,
                                                          const int* __restrict__ col,
                                                          const float* __restrict__ sup3,
                                                          float* __restrict__ out) {
    int e = blockIdx.x * 256 + threadIdx.x;
    if (e < N_EDGES) {
        int r = row[e], c = col[e];
        atomicAdd(&out[c], sup3[r]);
        atomicAdd(&out[N_NODES + c], sup3[N_NODES + r]);
    }
}

// ---------------- launch ----------------

extern "C" void kernel_launch(void* const* d_in, const int* in_sizes, int n_in,
                              void* d_out, int out_size, void* d_ws, size_t ws_size,
                              hipStream_t stream) {
    const float* x      = (const float*)d_in[0];
    const int*   ei     = (const int*)d_in[1];
    const float* W1     = (const float*)d_in[2];
    // d_in[3] = b1: per-feature bias before BN cancels exactly (shifts mean identically)
    const float* W2     = (const float*)d_in[4];
    // d_in[5] = b2: same cancellation
    const float* W3     = (const float*)d_in[6];
    const float* b3     = (const float*)d_in[7];
    const float* gamma1 = (const float*)d_in[8];
    const float* beta1  = (const float*)d_in[9];
    const float* gamma2 = (const float*)d_in[10];
    const float* beta2  = (const float*)d_in[11];
    const int* rowp = ei;             // edge_index[0]
    const int* colp = ei + N_EDGES;   // edge_index[1]

    float* sup      = (float*)d_ws;            // 12.8M floats (51.2 MB)
    float* agg      = sup + 12800000;          // 12.8M floats (51.2 MB)
    float* sup3     = agg + 12800000;          // 100k floats
    float* stats    = sup3 + 100000;           // 512 floats
    float* coef     = stats + 512;             // 512 floats
    int*   cnt      = (int*)(coef + 512);      // 50000
    int*   offsets  = cnt + N_NODES;           // 50001
    int*   cursor   = offsets + N_NODES + 1;   // 50000
    int*   srcbuf   = cursor + N_NODES;        // 800000
    int*   partials = srcbuf + N_EDGES;        // 196
    float* out      = (float*)d_out;

    hipMemsetAsync(cnt, 0, N_NODES * sizeof(int), stream);
    hipMemsetAsync(stats, 0, 512 * sizeof(float), stream);

    // CSR build (edge_index identical for both batches and all layers)
    hist_kernel       <<<3125,        256, 0, stream>>>(colp, cnt);
    scan_partials_sum <<<SCAN_BLOCKS, 256, 0, stream>>>(cnt, partials);
    scan_partials_scan<<<1,           256, 0, stream>>>(partials, offsets);
    scan_final        <<<SCAN_BLOCKS, 256, 0, stream>>>(cnt, partials, offsets, cursor);
    bucket_kernel     <<<3125,        256, 0, stream>>>(rowp, colp, cursor, srcbuf);

    // layer 1
    gemm128         <<<1563,  256, 0, stream>>>(x, W1, sup);
    aggregate_kernel<<<25000, 256, 0, stream>>>(sup, offsets, srcbuf, agg);
    bn_stats_kernel <<<512,   256, 0, stream>>>(agg, stats);
    bn_coef_kernel  <<<1,     128, 0, stream>>>(stats, gamma1, beta1, coef);
    bn_relu_kernel  <<<12500, 256, 0, stream>>>(agg, coef);

    // layer 2
    gemm128         <<<1563,  256, 0, stream>>>(agg, W2, sup);
    aggregate_kernel<<<25000, 256, 0, stream>>>(sup, offsets, srcbuf, agg);
    bn_stats_kernel <<<512,   256, 0, stream>>>(agg, stats + 256);
    bn_coef_kernel  <<<1,     128, 0, stream>>>(stats + 256, gamma2, beta2, coef + 256);
    bn_relu_kernel  <<<12500, 256, 0, stream>>>(agg, coef + 256);

    // layer 3 (output dim 1)
    gemv_kernel       <<<25000, 256, 0, stream>>>(agg, W3, sup3);
    out_init_kernel   <<<391,   256, 0, stream>>>(out, b3);
    scatter_out_kernel<<<3125,  256, 0, stream>>>(rowp, colp, sup3, out);
}

// Round 3
// 613.936 us; speedup vs baseline: 1.4438x; 1.2423x over previous
//
#include <hip/hip_runtime.h>

#define N_NODES 50000
#define N_EDGES 800000
#define FDIM 128
#define NROWS 100000   // B * N_NODES
#define BN_EPS 1e-5f
#define SCAN_BLOCKS 196   // ceil(50000 / 256)

typedef unsigned short ushort_t;
typedef unsigned int uint_t;

// round-to-nearest-even fp32 -> bf16
__device__ inline ushort_t f2bf(float f) {
    uint_t x = __float_as_uint(f);
    x += 0x7fffu + ((x >> 16) & 1u);
    return (ushort_t)(x >> 16);
}
__device__ inline float4 bf4_to_f4(ushort4 u) {
    float4 f;
    f.x = __uint_as_float((uint_t)u.x << 16);
    f.y = __uint_as_float((uint_t)u.y << 16);
    f.z = __uint_as_float((uint_t)u.z << 16);
    f.w = __uint_as_float((uint_t)u.w << 16);
    return f;
}

// ---------------- CSR build (per-destination buckets) ----------------

__global__ __launch_bounds__(256) void hist_kernel(const int* __restrict__ col,
                                                   int* __restrict__ cnt) {
    int e = blockIdx.x * 256 + threadIdx.x;
    if (e < N_EDGES) atomicAdd(&cnt[col[e]], 1);
}

__global__ __launch_bounds__(256) void scan_partials_sum(const int* __restrict__ cnt,
                                                         int* __restrict__ partials) {
    __shared__ int ws[4];
    int tid = threadIdx.x, lane = tid & 63, wid = tid >> 6;
    int i = blockIdx.x * 256 + tid;
    int v = (i < N_NODES) ? cnt[i] : 0;
    #pragma unroll
    for (int d = 32; d > 0; d >>= 1) v += __shfl_xor(v, d);
    if (lane == 0) ws[wid] = v;
    __syncthreads();
    if (tid == 0) partials[blockIdx.x] = ws[0] + ws[1] + ws[2] + ws[3];
}

__global__ __launch_bounds__(256) void scan_partials_scan(int* __restrict__ partials,
                                                          int* __restrict__ offsets) {
    __shared__ int ws[4];
    int tid = threadIdx.x, lane = tid & 63, wid = tid >> 6;
    int v = (tid < SCAN_BLOCKS) ? partials[tid] : 0;
    int x = v;
    #pragma unroll
    for (int d = 1; d < 64; d <<= 1) {
        int y = __shfl_up(x, d);
        if (lane >= d) x += y;
    }
    if (lane == 63) ws[wid] = x;
    __syncthreads();
    int woff = 0;
    for (int w = 0; w < wid; ++w) woff += ws[w];
    if (tid < SCAN_BLOCKS) partials[tid] = woff + x - v;   // exclusive
    if (tid == 255) offsets[N_NODES] = woff + x;           // grand total
}

__global__ __launch_bounds__(256) void scan_final(const int* __restrict__ cnt,
                                                  const int* __restrict__ partials,
                                                  int* __restrict__ offsets,
                                                  int* __restrict__ cursor) {
    __shared__ int ws[4];
    int tid = threadIdx.x, lane = tid & 63, wid = tid >> 6;
    int i = blockIdx.x * 256 + tid;
    int v = (i < N_NODES) ? cnt[i] : 0;
    int x = v;
    #pragma unroll
    for (int d = 1; d < 64; d <<= 1) {
        int y = __shfl_up(x, d);
        if (lane >= d) x += y;
    }
    if (lane == 63) ws[wid] = x;
    __syncthreads();
    int woff = 0;
    for (int w = 0; w < wid; ++w) woff += ws[w];
    if (i < N_NODES) {
        int off = partials[blockIdx.x] + woff + x - v;
        offsets[i] = off;
        cursor[i] = off;
    }
}

__global__ __launch_bounds__(256) void bucket_kernel(const int* __restrict__ row,
                                                     const int* __restrict__ col,
                                                     int* __restrict__ cursor,
                                                     int* __restrict__ srcbuf) {
    int e = blockIdx.x * 256 + threadIdx.x;
    if (e < N_EDGES) {
        int c = col[e];
        int p = atomicAdd(&cursor[c], 1);
        srcbuf[p] = row[e];
    }
}

// ---------------- GEMM: C_bf16[100000,128] = act(A[100000,128]) @ W[128,128] ----------------
// BN=true: A element gets relu(a*scale[f]+shift[f]) applied during LDS staging.
template <bool BN>
__global__ __launch_bounds__(256) void gemm128(const float* __restrict__ A,
                                               const float* __restrict__ Wm,
                                               const float* __restrict__ coef,
                                               ushort_t* __restrict__ C) {
    __shared__ float sA[64 * 128];
    __shared__ float sW[128 * 64];
    int tid = threadIdx.x;
    long r0 = (long)blockIdx.x * 64;
    const float4* A4 = (const float4*)A;
    const float4* W4 = (const float4*)Wm;
    const float4* coef4 = (const float4*)coef;
    float4* sA4 = (float4*)sA;
    float4* sW4 = (float4*)sW;

    #pragma unroll
    for (int i = 0; i < 8; ++i) {
        int li = tid + i * 256;          // 0..2047
        int r = li >> 5, kc = li & 31;   // row 0..63, k-chunk 0..31
        long gr = r0 + r;
        float4 v = make_float4(0.f, 0.f, 0.f, 0.f);
        if (gr < NROWS) v = A4[gr * 32 + kc];
        if (BN) {
            float4 sc = coef4[kc];
            float4 sh = coef4[32 + kc];
            v.x = fmaxf(v.x * sc.x + sh.x, 0.f);
            v.y = fmaxf(v.y * sc.y + sh.y, 0.f);
            v.z = fmaxf(v.z * sc.z + sh.z, 0.f);
            v.w = fmaxf(v.w * sc.w + sh.w, 0.f);
        }
        sA4[r * 32 + (kc ^ (r & 31))] = v;
    }

    int tc = tid & 15;   // 16 col-groups of 4 cols (within a 64-col half)
    int tr = tid >> 4;   // 16 row-groups of 4 rows
    ushort4* C4 = (ushort4*)C;

    for (int half = 0; half < 2; ++half) {
        __syncthreads();
        #pragma unroll
        for (int i = 0; i < 8; ++i) {
            int li = tid + i * 256;        // 0..2047
            int k = li >> 4, c4 = li & 15;
            sW4[li] = W4[k * 32 + half * 16 + c4];
        }
        __syncthreads();

        float acc[4][4] = {};
        #pragma unroll 2
        for (int kc = 0; kc < 32; ++kc) {
            float4 a0 = sA4[(tr * 4 + 0) * 32 + (kc ^ ((tr * 4 + 0) & 31))];
            float4 a1 = sA4[(tr * 4 + 1) * 32 + (kc ^ ((tr * 4 + 1) & 31))];
            float4 a2 = sA4[(tr * 4 + 2) * 32 + (kc ^ ((tr * 4 + 2) & 31))];
            float4 a3 = sA4[(tr * 4 + 3) * 32 + (kc ^ ((tr * 4 + 3) & 31))];
            float4 w0 = sW4[(kc * 4 + 0) * 16 + tc];
            float4 w1 = sW4[(kc * 4 + 1) * 16 + tc];
            float4 w2 = sW4[(kc * 4 + 2) * 16 + tc];
            float4 w3 = sW4[(kc * 4 + 3) * 16 + tc];
            #define GROW(r, a)                                             \
                acc[r][0] += a.x * w0.x + a.y * w1.x + a.z * w2.x + a.w * w3.x; \
                acc[r][1] += a.x * w0.y + a.y * w1.y + a.z * w2.y + a.w * w3.y; \
                acc[r][2] += a.x * w0.z + a.y * w1.z + a.z * w2.z + a.w * w3.z; \
                acc[r][3] += a.x * w0.w + a.y * w1.w + a.z * w2.w + a.w * w3.w;
            GROW(0, a0) GROW(1, a1) GROW(2, a2) GROW(3, a3)
            #undef GROW
        }

        #pragma unroll
        for (int r = 0; r < 4; ++r) {
            long gr = r0 + tr * 4 + r;
            if (gr < NROWS) {
                ushort4 o;
                o.x = f2bf(acc[r][0]);
                o.y = f2bf(acc[r][1]);
                o.z = f2bf(acc[r][2]);
                o.w = f2bf(acc[r][3]);
                C4[gr * 32 + half * 16 + tc] = o;
            }
        }
    }
}

// ---------------- Aggregate: agg[b,n,:] = sum over in-edges of sup_bf16[b,src,:] ----------------
// One wave per node, BOTH batches. Half-wave s handles edges j=2t+s; 32 lanes x ushort4
// cover the 256B bf16 row; 4 loads in flight per wave step. fp32 accumulate.
__global__ __launch_bounds__(256) void aggregate_bf16(const ushort_t* __restrict__ sup,
                                                      const int* __restrict__ offsets,
                                                      const int* __restrict__ srcbuf,
                                                      float* __restrict__ agg) {
    int lane = threadIdx.x & 63;
    int wid = threadIdx.x >> 6;
    int node = blockIdx.x * 4 + wid;
    if (node >= N_NODES) return;
    int s = lane >> 5;       // half-wave id
    int l32 = lane & 31;
    int beg = offsets[node], end = offsets[node + 1];
    const ushort4* sb0 = (const ushort4*)sup;                               // batch 0
    const ushort4* sb1 = (const ushort4*)(sup + (size_t)N_NODES * FDIM);    // batch 1
    float4 a0 = make_float4(0.f, 0.f, 0.f, 0.f);
    float4 a1 = make_float4(0.f, 0.f, 0.f, 0.f);
    for (int i = beg; i < end; i += 64) {
        int m = end - i; if (m > 64) m = 64;
        int idx = (i + lane < end) ? srcbuf[i + lane] : 0;  // coalesced index load
        int tmax = (m + 1) >> 1;
        #pragma unroll 2
        for (int t = 0; t < tmax; ++t) {
            int j = 2 * t + s;
            int r = __shfl(idx, j & 63);
            ushort4 u0 = sb0[(size_t)r * 32 + l32];
            ushort4 u1 = sb1[(size_t)r * 32 + l32];
            if (j < m) {
                float4 f0 = bf4_to_f4(u0);
                float4 f1 = bf4_to_f4(u1);
                a0.x += f0.x; a0.y += f0.y; a0.z += f0.z; a0.w += f0.w;
                a1.x += f1.x; a1.y += f1.y; a1.z += f1.z; a1.w += f1.w;
            }
        }
    }
    // combine the two half-wave partials (both halves end with the full sums)
    a0.x += __shfl_xor(a0.x, 32); a0.y += __shfl_xor(a0.y, 32);
    a0.z += __shfl_xor(a0.z, 32); a0.w += __shfl_xor(a0.w, 32);
    a1.x += __shfl_xor(a1.x, 32); a1.y += __shfl_xor(a1.y, 32);
    a1.z += __shfl_xor(a1.z, 32); a1.w += __shfl_xor(a1.w, 32);
    float4* ag = (float4*)agg;
    if (s == 0) ag[(size_t)node * 32 + l32] = a0;                       // batch 0 row
    else        ag[(size_t)(N_NODES + node) * 32 + l32] = a1;           // batch 1 row
}

// ---------------- BatchNorm stats (over raw agg) ----------------

__global__ __launch_bounds__(256) void bn_stats_kernel(const float* __restrict__ h,
                                                       float* __restrict__ stats) {
    __shared__ float ls[256], ls2[256];
    int tid = threadIdx.x;
    int f = tid & 127, half = tid >> 7;
    float s = 0.f, s2 = 0.f;
    for (int row = blockIdx.x * 2 + half; row < NROWS; row += gridDim.x * 2) {
        float v = h[(size_t)row * FDIM + f];
        s += v; s2 += v * v;
    }
    ls[tid] = s; ls2[tid] = s2;
    __syncthreads();
    if (tid < 128) {
        atomicAdd(&stats[f], ls[tid] + ls[tid + 128]);
        atomicAdd(&stats[128 + f], ls2[tid] + ls2[tid + 128]);
    }
}

__global__ void bn_coef_kernel(const float* __restrict__ stats,
                               const float* __restrict__ gamma,
                               const float* __restrict__ beta,
                               float* __restrict__ coef) {
    int f = threadIdx.x;
    if (f < 128) {
        float inv = 1.0f / (float)NROWS;
        float mean = stats[f] * inv;
        float var = stats[128 + f] * inv - mean * mean;  // biased var, matches jnp.var
        float scale = gamma[f] / sqrtf(var + BN_EPS);
        coef[f] = scale;
        coef[128 + f] = beta[f] - mean * scale;
    }
}

// ---------------- Layer 3: fused BN+ReLU GEMV + scalar scatter ----------------

__global__ __launch_bounds__(256) void gemv_bn_kernel(const float* __restrict__ h,
                                                      const float* __restrict__ coef,
                                                      const float* __restrict__ W3,
                                                      float* __restrict__ sup3) {
    int lane = threadIdx.x & 63, wid = threadIdx.x >> 6;
    int gw = blockIdx.x * 4 + wid;
    if (gw >= NROWS) return;
    float2 w  = ((const float2*)W3)[lane];
    float2 sc = ((const float2*)coef)[lane];
    float2 sh = ((const float2*)(coef + 128))[lane];
    float2 v  = ((const float2*)h)[(size_t)gw * 64 + lane];
    v.x = fmaxf(v.x * sc.x + sh.x, 0.f);
    v.y = fmaxf(v.y * sc.y + sh.y, 0.f);
    float s = v.x * w.x + v.y * w.y;
    #pragma unroll
    for (int d = 32; d > 0; d >>= 1) s += __shfl_xor(s, d);
    if (lane == 0) sup3[gw] = s;
}

__global__ void out_init_kernel(float* __restrict__ out, const float* __restrict__ b3) {
    int i = blockIdx.x * 256 + threadIdx.x;
    if (i < NROWS) out[i] = b3[0];
}

__global__ __launch_bounds__(256) void scatter_out_kernel(const int* __restrict__ row,
                                                          const int* __restrict__ col,
                                                          const float* __restrict__ sup3,
                                                          float* __restrict__ out) {
    int e = blockIdx.x * 256 + threadIdx.x;
    if (e < N_EDGES) {
        int r = row[e], c = col[e];
        atomicAdd(&out[c], sup3[r]);
        atomicAdd(&out[N_NODES + c], sup3[N_NODES + r]);
    }
}

// ---------------- launch ----------------

extern "C" void kernel_launch(void* const* d_in, const int* in_sizes, int n_in,
                              void* d_out, int out_size, void* d_ws, size_t ws_size,
                              hipStream_t stream) {
    const float* x      = (const float*)d_in[0];
    const int*   ei     = (const int*)d_in[1];
    const float* W1     = (const float*)d_in[2];
    // d_in[3] = b1: per-feature bias before BN cancels exactly (shifts mean identically)
    const float* W2     = (const float*)d_in[4];
    // d_in[5] = b2: same cancellation
    const float* W3     = (const float*)d_in[6];
    const float* b3     = (const float*)d_in[7];
    const float* gamma1 = (const float*)d_in[8];
    const float* beta1  = (const float*)d_in[9];
    const float* gamma2 = (const float*)d_in[10];
    const float* beta2  = (const float*)d_in[11];
    const int* rowp = ei;             // edge_index[0]
    const int* colp = ei + N_EDGES;   // edge_index[1]

    ushort_t* sup   = (ushort_t*)d_ws;              // 12.8M bf16 (25.6 MB)
    float* agg      = (float*)(sup + 12800000);     // 12.8M floats (51.2 MB)
    float* sup3     = agg + 12800000;               // 100k floats
    float* stats    = sup3 + 100000;                // 512 floats
    float* coef     = stats + 512;                  // 512 floats
    int*   cnt      = (int*)(coef + 512);           // 50000
    int*   offsets  = cnt + N_NODES;                // 50001
    int*   cursor   = offsets + N_NODES + 1;        // 50000
    int*   srcbuf   = cursor + N_NODES;             // 800000
    int*   partials = srcbuf + N_EDGES;             // 196
    float* out      = (float*)d_out;

    hipMemsetAsync(cnt, 0, N_NODES * sizeof(int), stream);
    hipMemsetAsync(stats, 0, 512 * sizeof(float), stream);

    // CSR build (edge_index identical for both batches and all layers)
    hist_kernel       <<<3125,        256, 0, stream>>>(colp, cnt);
    scan_partials_sum <<<SCAN_BLOCKS, 256, 0, stream>>>(cnt, partials);
    scan_partials_scan<<<1,           256, 0, stream>>>(partials, offsets);
    scan_final        <<<SCAN_BLOCKS, 256, 0, stream>>>(cnt, partials, offsets, cursor);
    bucket_kernel     <<<3125,        256, 0, stream>>>(rowp, colp, cursor, srcbuf);

    // layer 1: sup = x@W1 (bf16), agg = A·sup (fp32), stats
    gemm128<false> <<<1563,  256, 0, stream>>>(x, W1, nullptr, sup);
    aggregate_bf16 <<<12500, 256, 0, stream>>>(sup, offsets, srcbuf, agg);
    bn_stats_kernel<<<512,   256, 0, stream>>>(agg, stats);
    bn_coef_kernel <<<1,     128, 0, stream>>>(stats, gamma1, beta1, coef);

    // layer 2: sup = relu(bn(agg))@W2 (BN fused into GEMM staging), agg = A·sup, stats
    gemm128<true>  <<<1563,  256, 0, stream>>>(agg, W2, coef, sup);
    aggregate_bf16 <<<12500, 256, 0, stream>>>(sup, offsets, srcbuf, agg);
    bn_stats_kernel<<<512,   256, 0, stream>>>(agg, stats + 256);
    bn_coef_kernel <<<1,     128, 0, stream>>>(stats + 256, gamma2, beta2, coef + 256);

    // layer 3: sup3 = relu(bn(agg))@W3 (fused GEMV), out = A·sup3 + b3
    gemv_bn_kernel    <<<25000, 256, 0, stream>>>(agg, coef + 256, W3, sup3);
    out_init_kernel   <<<391,   256, 0, stream>>>(out, b3);
    scatter_out_kernel<<<3125,  256, 0, stream>>>(rowp, colp, sup3, out);
}

// Round 4
// 541.904 us; speedup vs baseline: 1.6357x; 1.1329x over previous
//
#include <hip/hip_runtime.h>

#define N_NODES 50000
#define N_EDGES 800000
#define FDIM 128
#define NROWS 100000   // B * N_NODES
#define BN_EPS 1e-5f
#define SCAN_BLOCKS 196   // ceil(50000 / 256)

typedef unsigned short ushort_t;
typedef unsigned int uint_t;

// round-to-nearest-even fp32 -> bf16
__device__ inline ushort_t f2bf(float f) {
    uint_t x = __float_as_uint(f);
    x += 0x7fffu + ((x >> 16) & 1u);
    return (ushort_t)(x >> 16);
}
__device__ inline float4 bf4_to_f4(ushort4 u) {
    float4 f;
    f.x = __uint_as_float((uint_t)u.x << 16);
    f.y = __uint_as_float((uint_t)u.y << 16);
    f.z = __uint_as_float((uint_t)u.z << 16);
    f.w = __uint_as_float((uint_t)u.w << 16);
    return f;
}

// ---------------- CSR build (per-destination buckets) ----------------

__global__ __launch_bounds__(256) void hist_kernel(const int* __restrict__ col,
                                                   int* __restrict__ cnt) {
    int e = blockIdx.x * 256 + threadIdx.x;
    if (e < N_EDGES) atomicAdd(&cnt[col[e]], 1);
}

__global__ __launch_bounds__(256) void scan_partials_sum(const int* __restrict__ cnt,
                                                         int* __restrict__ partials) {
    __shared__ int ws[4];
    int tid = threadIdx.x, lane = tid & 63, wid = tid >> 6;
    int i = blockIdx.x * 256 + tid;
    int v = (i < N_NODES) ? cnt[i] : 0;
    #pragma unroll
    for (int d = 32; d > 0; d >>= 1) v += __shfl_xor(v, d);
    if (lane == 0) ws[wid] = v;
    __syncthreads();
    if (tid == 0) partials[blockIdx.x] = ws[0] + ws[1] + ws[2] + ws[3];
}

__global__ __launch_bounds__(256) void scan_partials_scan(int* __restrict__ partials,
                                                          int* __restrict__ offsets) {
    __shared__ int ws[4];
    int tid = threadIdx.x, lane = tid & 63, wid = tid >> 6;
    int v = (tid < SCAN_BLOCKS) ? partials[tid] : 0;
    int x = v;
    #pragma unroll
    for (int d = 1; d < 64; d <<= 1) {
        int y = __shfl_up(x, d);
        if (lane >= d) x += y;
    }
    if (lane == 63) ws[wid] = x;
    __syncthreads();
    int woff = 0;
    for (int w = 0; w < wid; ++w) woff += ws[w];
    if (tid < SCAN_BLOCKS) partials[tid] = woff + x - v;   // exclusive
    if (tid == 255) offsets[N_NODES] = woff + x;           // grand total
}

__global__ __launch_bounds__(256) void scan_final(const int* __restrict__ cnt,
                                                  const int* __restrict__ partials,
                                                  int* __restrict__ offsets,
                                                  int* __restrict__ cursor) {
    __shared__ int ws[4];
    int tid = threadIdx.x, lane = tid & 63, wid = tid >> 6;
    int i = blockIdx.x * 256 + tid;
    int v = (i < N_NODES) ? cnt[i] : 0;
    int x = v;
    #pragma unroll
    for (int d = 1; d < 64; d <<= 1) {
        int y = __shfl_up(x, d);
        if (lane >= d) x += y;
    }
    if (lane == 63) ws[wid] = x;
    __syncthreads();
    int woff = 0;
    for (int w = 0; w < wid; ++w) woff += ws[w];
    if (i < N_NODES) {
        int off = partials[blockIdx.x] + woff + x - v;
        offsets[i] = off;
        cursor[i] = off;
    }
}

__global__ __launch_bounds__(256) void bucket_kernel(const int* __restrict__ row,
                                                     const int* __restrict__ col,
                                                     int* __restrict__ cursor,
                                                     int* __restrict__ srcbuf) {
    int e = blockIdx.x * 256 + threadIdx.x;
    if (e < N_EDGES) {
        int c = col[e];
        int p = atomicAdd(&cursor[c], 1);
        srcbuf[p] = row[e];
    }
}

// ---------------- GEMM: C_bf16[100000,128] = act(A[100000,128]) @ W[128,128] ----------------
template <bool BN>
__global__ __launch_bounds__(256) void gemm128(const float* __restrict__ A,
                                               const float* __restrict__ Wm,
                                               const float* __restrict__ coef,
                                               ushort_t* __restrict__ C) {
    __shared__ float sA[64 * 128];
    __shared__ float sW[128 * 64];
    int tid = threadIdx.x;
    long r0 = (long)blockIdx.x * 64;
    const float4* A4 = (const float4*)A;
    const float4* W4 = (const float4*)Wm;
    const float4* coef4 = (const float4*)coef;
    float4* sA4 = (float4*)sA;
    float4* sW4 = (float4*)sW;

    #pragma unroll
    for (int i = 0; i < 8; ++i) {
        int li = tid + i * 256;          // 0..2047
        int r = li >> 5, kc = li & 31;   // row 0..63, k-chunk 0..31
        long gr = r0 + r;
        float4 v = make_float4(0.f, 0.f, 0.f, 0.f);
        if (gr < NROWS) v = A4[gr * 32 + kc];
        if (BN) {
            float4 sc = coef4[kc];
            float4 sh = coef4[32 + kc];
            v.x = fmaxf(v.x * sc.x + sh.x, 0.f);
            v.y = fmaxf(v.y * sc.y + sh.y, 0.f);
            v.z = fmaxf(v.z * sc.z + sh.z, 0.f);
            v.w = fmaxf(v.w * sc.w + sh.w, 0.f);
        }
        sA4[r * 32 + (kc ^ (r & 31))] = v;
    }

    int tc = tid & 15;   // 16 col-groups of 4 cols (within a 64-col half)
    int tr = tid >> 4;   // 16 row-groups of 4 rows
    ushort4* C4 = (ushort4*)C;

    for (int half = 0; half < 2; ++half) {
        __syncthreads();
        #pragma unroll
        for (int i = 0; i < 8; ++i) {
            int li = tid + i * 256;        // 0..2047
            int k = li >> 4, c4 = li & 15;
            sW4[li] = W4[k * 32 + half * 16 + c4];
        }
        __syncthreads();

        float acc[4][4] = {};
        #pragma unroll 2
        for (int kc = 0; kc < 32; ++kc) {
            float4 a0 = sA4[(tr * 4 + 0) * 32 + (kc ^ ((tr * 4 + 0) & 31))];
            float4 a1 = sA4[(tr * 4 + 1) * 32 + (kc ^ ((tr * 4 + 1) & 31))];
            float4 a2 = sA4[(tr * 4 + 2) * 32 + (kc ^ ((tr * 4 + 2) & 31))];
            float4 a3 = sA4[(tr * 4 + 3) * 32 + (kc ^ ((tr * 4 + 3) & 31))];
            float4 w0 = sW4[(kc * 4 + 0) * 16 + tc];
            float4 w1 = sW4[(kc * 4 + 1) * 16 + tc];
            float4 w2 = sW4[(kc * 4 + 2) * 16 + tc];
            float4 w3 = sW4[(kc * 4 + 3) * 16 + tc];
            #define GROW(r, a)                                             \
                acc[r][0] += a.x * w0.x + a.y * w1.x + a.z * w2.x + a.w * w3.x; \
                acc[r][1] += a.x * w0.y + a.y * w1.y + a.z * w2.y + a.w * w3.y; \
                acc[r][2] += a.x * w0.z + a.y * w1.z + a.z * w2.z + a.w * w3.z; \
                acc[r][3] += a.x * w0.w + a.y * w1.w + a.z * w2.w + a.w * w3.w;
            GROW(0, a0) GROW(1, a1) GROW(2, a2) GROW(3, a3)
            #undef GROW
        }

        #pragma unroll
        for (int r = 0; r < 4; ++r) {
            long gr = r0 + tr * 4 + r;
            if (gr < NROWS) {
                ushort4 o;
                o.x = f2bf(acc[r][0]);
                o.y = f2bf(acc[r][1]);
                o.z = f2bf(acc[r][2]);
                o.w = f2bf(acc[r][3]);
                C4[gr * 32 + half * 16 + tc] = o;
            }
        }
    }
}

// ---------------- Aggregate: agg[b,n,:] = sum over in-edges of sup_bf16[b,src,:] ----------------
__global__ __launch_bounds__(256) void aggregate_bf16(const ushort_t* __restrict__ sup,
                                                      const int* __restrict__ offsets,
                                                      const int* __restrict__ srcbuf,
                                                      float* __restrict__ agg) {
    int lane = threadIdx.x & 63;
    int wid = threadIdx.x >> 6;
    int node = blockIdx.x * 4 + wid;
    if (node >= N_NODES) return;
    int s = lane >> 5;       // half-wave id
    int l32 = lane & 31;
    int beg = offsets[node], end = offsets[node + 1];
    const ushort4* sb0 = (const ushort4*)sup;                               // batch 0
    const ushort4* sb1 = (const ushort4*)(sup + (size_t)N_NODES * FDIM);    // batch 1
    float4 a0 = make_float4(0.f, 0.f, 0.f, 0.f);
    float4 a1 = make_float4(0.f, 0.f, 0.f, 0.f);
    for (int i = beg; i < end; i += 64) {
        int m = end - i; if (m > 64) m = 64;
        int idx = (i + lane < end) ? srcbuf[i + lane] : 0;  // coalesced index load
        int tmax = (m + 1) >> 1;
        #pragma unroll 2
        for (int t = 0; t < tmax; ++t) {
            int j = 2 * t + s;
            int r = __shfl(idx, j & 63);
            ushort4 u0 = sb0[(size_t)r * 32 + l32];
            ushort4 u1 = sb1[(size_t)r * 32 + l32];
            if (j < m) {
                float4 f0 = bf4_to_f4(u0);
                float4 f1 = bf4_to_f4(u1);
                a0.x += f0.x; a0.y += f0.y; a0.z += f0.z; a0.w += f0.w;
                a1.x += f1.x; a1.y += f1.y; a1.z += f1.z; a1.w += f1.w;
            }
        }
    }
    a0.x += __shfl_xor(a0.x, 32); a0.y += __shfl_xor(a0.y, 32);
    a0.z += __shfl_xor(a0.z, 32); a0.w += __shfl_xor(a0.w, 32);
    a1.x += __shfl_xor(a1.x, 32); a1.y += __shfl_xor(a1.y, 32);
    a1.z += __shfl_xor(a1.z, 32); a1.w += __shfl_xor(a1.w, 32);
    float4* ag = (float4*)agg;
    if (s == 0) ag[(size_t)node * 32 + l32] = a0;                       // batch 0 row
    else        ag[(size_t)(N_NODES + node) * 32 + l32] = a1;           // batch 1 row
}

// ---------------- BatchNorm stats (over raw agg) ----------------

__global__ __launch_bounds__(256) void bn_stats_kernel(const float* __restrict__ h,
                                                       float* __restrict__ stats) {
    __shared__ float ls[256], ls2[256];
    int tid = threadIdx.x;
    int f = tid & 127, half = tid >> 7;
    float s = 0.f, s2 = 0.f;
    for (int row = blockIdx.x * 2 + half; row < NROWS; row += gridDim.x * 2) {
        float v = h[(size_t)row * FDIM + f];
        s += v; s2 += v * v;
    }
    ls[tid] = s; ls2[tid] = s2;
    __syncthreads();
    if (tid < 128) {
        atomicAdd(&stats[f], ls[tid] + ls[tid + 128]);
        atomicAdd(&stats[128 + f], ls2[tid] + ls2[tid + 128]);
    }
}

__global__ void bn_coef_kernel(const float* __restrict__ stats,
                               const float* __restrict__ gamma,
                               const float* __restrict__ beta,
                               float* __restrict__ coef) {
    int f = threadIdx.x;
    if (f < 128) {
        float inv = 1.0f / (float)NROWS;
        float mean = stats[f] * inv;
        float var = stats[128 + f] * inv - mean * mean;  // biased var, matches jnp.var
        float scale = gamma[f] / sqrtf(var + BN_EPS);
        coef[f] = scale;
        coef[128 + f] = beta[f] - mean * scale;
    }
}

// ---------------- Layer 3: fused BN+ReLU GEMV + CSR gather ----------------

__global__ __launch_bounds__(256) void gemv_bn_kernel(const float* __restrict__ h,
                                                      const float* __restrict__ coef,
                                                      const float* __restrict__ W3,
                                                      float* __restrict__ sup3) {
    int lane = threadIdx.x & 63, wid = threadIdx.x >> 6;
    int gw = blockIdx.x * 4 + wid;
    if (gw >= NROWS) return;
    float2 w  = ((const float2*)W3)[lane];
    float2 sc = ((const float2*)coef)[lane];
    float2 sh = ((const float2*)(coef + 128))[lane];
    float2 v  = ((const float2*)h)[(size_t)gw * 64 + lane];
    v.x = fmaxf(v.x * sc.x + sh.x, 0.f);
    v.y = fmaxf(v.y * sc.y + sh.y, 0.f);
    float s = v.x * w.x + v.y * w.y;
    #pragma unroll
    for (int d = 32; d > 0; d >>= 1) s += __shfl_xor(s, d);
    if (lane == 0) sup3[gw] = s;
}

// out[b,n] = b3 + sum over CSR in-edges of sup3[b, src]. One thread per node,
// both batches share the index loads. sup3 (400KB) + srcbuf (3.2MB) are L2/L3
// resident -> latency-bound gather, no atomics, no RMW write amplification.
__global__ __launch_bounds__(256) void gather_out_kernel(const int* __restrict__ offsets,
                                                         const int* __restrict__ srcbuf,
                                                         const float* __restrict__ sup3,
                                                         const float* __restrict__ b3,
                                                         float* __restrict__ out) {
    int n = blockIdx.x * 256 + threadIdx.x;
    if (n >= N_NODES) return;
    int beg = offsets[n], end = offsets[n + 1];
    float s0 = 0.f, s1 = 0.f;
    for (int i = beg; i < end; ++i) {
        int r = srcbuf[i];
        s0 += sup3[r];
        s1 += sup3[N_NODES + r];
    }
    float b = b3[0];
    out[n] = s0 + b;
    out[N_NODES + n] = s1 + b;
}

// ---------------- launch ----------------

extern "C" void kernel_launch(void* const* d_in, const int* in_sizes, int n_in,
                              void* d_out, int out_size, void* d_ws, size_t ws_size,
                              hipStream_t stream) {
    const float* x      = (const float*)d_in[0];
    const int*   ei     = (const int*)d_in[1];
    const float* W1     = (const float*)d_in[2];
    // d_in[3] = b1: per-feature bias before BN cancels exactly (shifts mean identically)
    const float* W2     = (const float*)d_in[4];
    // d_in[5] = b2: same cancellation
    const float* W3     = (const float*)d_in[6];
    const float* b3     = (const float*)d_in[7];
    const float* gamma1 = (const float*)d_in[8];
    const float* beta1  = (const float*)d_in[9];
    const float* gamma2 = (const float*)d_in[10];
    const float* beta2  = (const float*)d_in[11];
    const int* rowp = ei;             // edge_index[0]
    const int* colp = ei + N_EDGES;   // edge_index[1]

    ushort_t* sup   = (ushort_t*)d_ws;              // 12.8M bf16 (25.6 MB)
    float* agg      = (float*)(sup + 12800000);     // 12.8M floats (51.2 MB)
    float* sup3     = agg + 12800000;               // 100k floats
    float* stats    = sup3 + 100000;                // 512 floats
    float* coef     = stats + 512;                  // 512 floats
    int*   cnt      = (int*)(coef + 512);           // 50000
    int*   offsets  = cnt + N_NODES;                // 50001
    int*   cursor   = offsets + N_NODES + 1;        // 50000
    int*   srcbuf   = cursor + N_NODES;             // 800000
    int*   partials = srcbuf + N_EDGES;             // 196
    float* out      = (float*)d_out;

    hipMemsetAsync(cnt, 0, N_NODES * sizeof(int), stream);
    hipMemsetAsync(stats, 0, 512 * sizeof(float), stream);

    // CSR build (edge_index identical for both batches and all layers)
    hist_kernel       <<<3125,        256, 0, stream>>>(colp, cnt);
    scan_partials_sum <<<SCAN_BLOCKS, 256, 0, stream>>>(cnt, partials);
    scan_partials_scan<<<1,           256, 0, stream>>>(partials, offsets);
    scan_final        <<<SCAN_BLOCKS, 256, 0, stream>>>(cnt, partials, offsets, cursor);
    bucket_kernel     <<<3125,        256, 0, stream>>>(rowp, colp, cursor, srcbuf);

    // layer 1: sup = x@W1 (bf16), agg = A·sup (fp32), stats
    gemm128<false> <<<1563,  256, 0, stream>>>(x, W1, nullptr, sup);
    aggregate_bf16 <<<12500, 256, 0, stream>>>(sup, offsets, srcbuf, agg);
    bn_stats_kernel<<<512,   256, 0, stream>>>(agg, stats);
    bn_coef_kernel <<<1,     128, 0, stream>>>(stats, gamma1, beta1, coef);

    // layer 2: sup = relu(bn(agg))@W2 (BN fused into GEMM staging), agg = A·sup, stats
    gemm128<true>  <<<1563,  256, 0, stream>>>(agg, W2, coef, sup);
    aggregate_bf16 <<<12500, 256, 0, stream>>>(sup, offsets, srcbuf, agg);
    bn_stats_kernel<<<512,   256, 0, stream>>>(agg, stats + 256);
    bn_coef_kernel <<<1,     128, 0, stream>>>(stats + 256, gamma2, beta2, coef + 256);

    // layer 3: sup3 = relu(bn(agg))@W3 (fused GEMV), out = A·sup3 + b3 (CSR gather)
    gemv_bn_kernel   <<<25000, 256, 0, stream>>>(agg, coef + 256, W3, sup3);
    gather_out_kernel<<<SCAN_BLOCKS, 256, 0, stream>>>(offsets, srcbuf, sup3, b3, out);
}

// Round 5
// 468.220 us; speedup vs baseline: 1.8931x; 1.1574x over previous
//
#include <hip/hip_runtime.h>

#define N_NODES 50000
#define N_EDGES 800000
#define FDIM 128
#define NROWS 100000   // B * N_NODES
#define BN_EPS 1e-5f
#define SCAN_BLOCKS 196   // ceil(50000 / 256)

typedef unsigned short ushort_t;
typedef unsigned int uint_t;
typedef __attribute__((ext_vector_type(8))) short bf16x8;   // 8 bf16 = 4 VGPRs (MFMA A/B frag)
typedef __attribute__((ext_vector_type(4))) float f32x4;    // MFMA C/D frag

// round-to-nearest-even fp32 -> bf16
__device__ inline ushort_t f2bf(float f) {
    uint_t x = __float_as_uint(f);
    x += 0x7fffu + ((x >> 16) & 1u);
    return (ushort_t)(x >> 16);
}
__device__ inline float4 bf4_to_f4(ushort4 u) {
    float4 f;
    f.x = __uint_as_float((uint_t)u.x << 16);
    f.y = __uint_as_float((uint_t)u.y << 16);
    f.z = __uint_as_float((uint_t)u.z << 16);
    f.w = __uint_as_float((uint_t)u.w << 16);
    return f;
}
// split-bf16: f = hi + lo with |err| ~ 2^-18 |f|
__device__ inline void split4(float4 v, bf16x8& hi, bf16x8& lo, int base) {
    float f[4] = {v.x, v.y, v.z, v.w};
    #pragma unroll
    for (int t = 0; t < 4; ++t) {
        ushort_t h = f2bf(f[t]);
        float fh = __uint_as_float((uint_t)h << 16);
        ushort_t l = f2bf(f[t] - fh);
        hi[base + t] = (short)h;
        lo[base + t] = (short)l;
    }
}

// ---------------- CSR build (per-destination buckets) ----------------

__global__ __launch_bounds__(256) void hist_kernel(const int* __restrict__ col,
                                                   int* __restrict__ cnt) {
    int e = blockIdx.x * 256 + threadIdx.x;
    if (e < N_EDGES) atomicAdd(&cnt[col[e]], 1);
}

__global__ __launch_bounds__(256) void scan_partials_sum(const int* __restrict__ cnt,
                                                         int* __restrict__ partials) {
    __shared__ int ws[4];
    int tid = threadIdx.x, lane = tid & 63, wid = tid >> 6;
    int i = blockIdx.x * 256 + tid;
    int v = (i < N_NODES) ? cnt[i] : 0;
    #pragma unroll
    for (int d = 32; d > 0; d >>= 1) v += __shfl_xor(v, d);
    if (lane == 0) ws[wid] = v;
    __syncthreads();
    if (tid == 0) partials[blockIdx.x] = ws[0] + ws[1] + ws[2] + ws[3];
}

__global__ __launch_bounds__(256) void scan_partials_scan(int* __restrict__ partials,
                                                          int* __restrict__ offsets) {
    __shared__ int ws[4];
    int tid = threadIdx.x, lane = tid & 63, wid = tid >> 6;
    int v = (tid < SCAN_BLOCKS) ? partials[tid] : 0;
    int x = v;
    #pragma unroll
    for (int d = 1; d < 64; d <<= 1) {
        int y = __shfl_up(x, d);
        if (lane >= d) x += y;
    }
    if (lane == 63) ws[wid] = x;
    __syncthreads();
    int woff = 0;
    for (int w = 0; w < wid; ++w) woff += ws[w];
    if (tid < SCAN_BLOCKS) partials[tid] = woff + x - v;   // exclusive
    if (tid == 255) offsets[N_NODES] = woff + x;           // grand total
}

__global__ __launch_bounds__(256) void scan_final(const int* __restrict__ cnt,
                                                  const int* __restrict__ partials,
                                                  int* __restrict__ offsets,
                                                  int* __restrict__ cursor) {
    __shared__ int ws[4];
    int tid = threadIdx.x, lane = tid & 63, wid = tid >> 6;
    int i = blockIdx.x * 256 + tid;
    int v = (i < N_NODES) ? cnt[i] : 0;
    int x = v;
    #pragma unroll
    for (int d = 1; d < 64; d <<= 1) {
        int y = __shfl_up(x, d);
        if (lane >= d) x += y;
    }
    if (lane == 63) ws[wid] = x;
    __syncthreads();
    int woff = 0;
    for (int w = 0; w < wid; ++w) woff += ws[w];
    if (i < N_NODES) {
        int off = partials[blockIdx.x] + woff + x - v;
        offsets[i] = off;
        cursor[i] = off;
    }
}

__global__ __launch_bounds__(256) void bucket_kernel(const int* __restrict__ row,
                                                     const int* __restrict__ col,
                                                     int* __restrict__ cursor,
                                                     int* __restrict__ srcbuf) {
    int e = blockIdx.x * 256 + threadIdx.x;
    if (e < N_EDGES) {
        int c = col[e];
        int p = atomicAdd(&cursor[c], 1);
        srcbuf[p] = row[e];
    }
}

// ---------------- W pre-transform: Wt[n][k] split into hi/lo bf16 planes ----------------
// wt layout (ushort): [which(2)][plane(2)][n(128)][k(128)]
__global__ __launch_bounds__(256) void wsplit_kernel(const float* __restrict__ W1,
                                                     const float* __restrict__ W2,
                                                     ushort_t* __restrict__ wt) {
    int idx = blockIdx.x * 256 + threadIdx.x;   // 0..32767
    int which = idx >> 14;
    int e = idx & 16383;                         // e = k*128 + n (coalesced read)
    int k = e >> 7, n = e & 127;
    float f = (which ? W2 : W1)[e];
    ushort_t h = f2bf(f);
    float fh = __uint_as_float((uint_t)h << 16);
    ushort_t l = f2bf(f - fh);
    size_t base = (size_t)which * 32768;
    wt[base + n * 128 + k] = h;                  // hi plane
    wt[base + 16384 + n * 128 + k] = l;          // lo plane
}

// ---------------- GEMM via split-bf16 MFMA ----------------
// C_bf16[100000,128] = act(A[100000,128]) @ W[128,128], fp32-grade accuracy:
// A = Ah+Al, W = Wh+Wl (bf16 splits); A*W ~ Ah*Wh + Ah*Wl + Al*Wh (err ~2^-18).
// LDS 64KB: A-split 64x128 (staged once) + W-split 64-col half (per half).
// 16B-block XOR swizzle (j ^ row&15) -> 2-way bank aliasing only (free).
template <bool BN>
__global__ __launch_bounds__(256) void gemm_mfma(const float* __restrict__ A,
                                                 const ushort_t* __restrict__ wt,
                                                 const float* __restrict__ coef,
                                                 ushort_t* __restrict__ C) {
    __shared__ short lds[32768];  // Ah[0,8192) Al[8192,16384) Wh[16384,24576) Wl[24576,32768)
    int tid = threadIdx.x;
    long r0 = (long)blockIdx.x * 64;
    const float4* A4 = (const float4*)A;
    const float4* coef4 = (const float4*)coef;

    // ---- stage A split: 1024 tasks of one 16B bf16 block (8 elems) each ----
    #pragma unroll
    for (int i = 0; i < 4; ++i) {
        int li = tid + i * 256;
        int r = li >> 4, j = li & 15;        // row 0..63, k-block 0..15
        long gr = r0 + r;
        float4 va = make_float4(0.f, 0.f, 0.f, 0.f), vb = va;
        if (gr < NROWS) { va = A4[gr * 32 + j * 2]; vb = A4[gr * 32 + j * 2 + 1]; }
        if (BN) {
            float4 sc = coef4[j * 2], sh = coef4[32 + j * 2];
            va.x = fmaxf(va.x * sc.x + sh.x, 0.f);
            va.y = fmaxf(va.y * sc.y + sh.y, 0.f);
            va.z = fmaxf(va.z * sc.z + sh.z, 0.f);
            va.w = fmaxf(va.w * sc.w + sh.w, 0.f);
            sc = coef4[j * 2 + 1]; sh = coef4[32 + j * 2 + 1];
            vb.x = fmaxf(vb.x * sc.x + sh.x, 0.f);
            vb.y = fmaxf(vb.y * sc.y + sh.y, 0.f);
            vb.z = fmaxf(vb.z * sc.z + sh.z, 0.f);
            vb.w = fmaxf(vb.w * sc.w + sh.w, 0.f);
        }
        bf16x8 vh, vl;
        split4(va, vh, vl, 0);
        split4(vb, vh, vl, 4);
        int off = r * 128 + ((j ^ (r & 15)) * 8);
        *(bf16x8*)&lds[off] = vh;
        *(bf16x8*)&lds[8192 + off] = vl;
    }

    int w = tid >> 6, l = tid & 63;
    int m = l & 15, q = l >> 4;
    for (int half = 0; half < 2; ++half) {
        __syncthreads();
        // ---- stage W-split half: 2048 tasks (plane, n_loc, k-block) ----
        #pragma unroll
        for (int i = 0; i < 8; ++i) {
            int li = tid + i * 256;
            int p = li >> 10;                 // 0=hi 1=lo
            int rest = li & 1023;
            int nl = rest >> 4, j = rest & 15;
            bf16x8 v = *(const bf16x8*)&wt[(size_t)p * 16384 + (half * 64 + nl) * 128 + j * 8];
            *(bf16x8*)&lds[16384 + p * 8192 + nl * 128 + ((j ^ (nl & 15)) * 8)] = v;
        }
        __syncthreads();

        // ---- MFMA: wave w -> rows [w*16, w*16+16), 4 col-tiles of 16 ----
        f32x4 acc[4] = {};
        #pragma unroll
        for (int s = 0; s < 4; ++s) {
            int x = (s * 4 + q) ^ m;
            int aoff = (w * 16 + m) * 128 + x * 8;
            bf16x8 ah = *(const bf16x8*)&lds[aoff];
            bf16x8 al = *(const bf16x8*)&lds[8192 + aoff];
            #pragma unroll
            for (int c = 0; c < 4; ++c) {
                int boff = 16384 + (c * 16 + m) * 128 + x * 8;
                bf16x8 bh = *(const bf16x8*)&lds[boff];
                bf16x8 bl = *(const bf16x8*)&lds[8192 + boff];
                acc[c] = __builtin_amdgcn_mfma_f32_16x16x32_bf16(al, bh, acc[c], 0, 0, 0);
                acc[c] = __builtin_amdgcn_mfma_f32_16x16x32_bf16(ah, bl, acc[c], 0, 0, 0);
                acc[c] = __builtin_amdgcn_mfma_f32_16x16x32_bf16(ah, bh, acc[c], 0, 0, 0);
            }
        }

        // ---- write C (bf16): lane holds C[row=q*4+r][col=m] per tile ----
        #pragma unroll
        for (int c = 0; c < 4; ++c) {
            #pragma unroll
            for (int r = 0; r < 4; ++r) {
                long gr = r0 + w * 16 + q * 4 + r;
                if (gr < NROWS)
                    C[gr * 128 + half * 64 + c * 16 + m] = f2bf(acc[c][r]);
            }
        }
    }
}

// ---------------- Aggregate: agg[b,n,:] = sum over in-edges of sup_bf16[b,src,:] ----------------
__global__ __launch_bounds__(256) void aggregate_bf16(const ushort_t* __restrict__ sup,
                                                      const int* __restrict__ offsets,
                                                      const int* __restrict__ srcbuf,
                                                      float* __restrict__ agg) {
    int lane = threadIdx.x & 63;
    int wid = threadIdx.x >> 6;
    int node = blockIdx.x * 4 + wid;
    if (node >= N_NODES) return;
    int s = lane >> 5;       // half-wave id
    int l32 = lane & 31;
    int beg = offsets[node], end = offsets[node + 1];
    const ushort4* sb0 = (const ushort4*)sup;                               // batch 0
    const ushort4* sb1 = (const ushort4*)(sup + (size_t)N_NODES * FDIM);    // batch 1
    float4 a0 = make_float4(0.f, 0.f, 0.f, 0.f);
    float4 a1 = make_float4(0.f, 0.f, 0.f, 0.f);
    for (int i = beg; i < end; i += 64) {
        int m = end - i; if (m > 64) m = 64;
        int idx = (i + lane < end) ? srcbuf[i + lane] : 0;  // coalesced index load
        int tmax = (m + 1) >> 1;
        #pragma unroll 2
        for (int t = 0; t < tmax; ++t) {
            int j = 2 * t + s;
            int r = __shfl(idx, j & 63);
            ushort4 u0 = sb0[(size_t)r * 32 + l32];
            ushort4 u1 = sb1[(size_t)r * 32 + l32];
            if (j < m) {
                float4 f0 = bf4_to_f4(u0);
                float4 f1 = bf4_to_f4(u1);
                a0.x += f0.x; a0.y += f0.y; a0.z += f0.z; a0.w += f0.w;
                a1.x += f1.x; a1.y += f1.y; a1.z += f1.z; a1.w += f1.w;
            }
        }
    }
    a0.x += __shfl_xor(a0.x, 32); a0.y += __shfl_xor(a0.y, 32);
    a0.z += __shfl_xor(a0.z, 32); a0.w += __shfl_xor(a0.w, 32);
    a1.x += __shfl_xor(a1.x, 32); a1.y += __shfl_xor(a1.y, 32);
    a1.z += __shfl_xor(a1.z, 32); a1.w += __shfl_xor(a1.w, 32);
    float4* ag = (float4*)agg;
    if (s == 0) ag[(size_t)node * 32 + l32] = a0;                       // batch 0 row
    else        ag[(size_t)(N_NODES + node) * 32 + l32] = a1;           // batch 1 row
}

// ---------------- BatchNorm stats (over raw agg) ----------------

__global__ __launch_bounds__(256) void bn_stats_kernel(const float* __restrict__ h,
                                                       float* __restrict__ stats) {
    __shared__ float ls[256], ls2[256];
    int tid = threadIdx.x;
    int f = tid & 127, half = tid >> 7;
    float s = 0.f, s2 = 0.f;
    for (int row = blockIdx.x * 2 + half; row < NROWS; row += gridDim.x * 2) {
        float v = h[(size_t)row * FDIM + f];
        s += v; s2 += v * v;
    }
    ls[tid] = s; ls2[tid] = s2;
    __syncthreads();
    if (tid < 128) {
        atomicAdd(&stats[f], ls[tid] + ls[tid + 128]);
        atomicAdd(&stats[128 + f], ls2[tid] + ls2[tid + 128]);
    }
}

__global__ void bn_coef_kernel(const float* __restrict__ stats,
                               const float* __restrict__ gamma,
                               const float* __restrict__ beta,
                               float* __restrict__ coef) {
    int f = threadIdx.x;
    if (f < 128) {
        float inv = 1.0f / (float)NROWS;
        float mean = stats[f] * inv;
        float var = stats[128 + f] * inv - mean * mean;  // biased var, matches jnp.var
        float scale = gamma[f] / sqrtf(var + BN_EPS);
        coef[f] = scale;
        coef[128 + f] = beta[f] - mean * scale;
    }
}

// ---------------- Layer 3: fused BN+ReLU GEMV + CSR gather ----------------

__global__ __launch_bounds__(256) void gemv_bn_kernel(const float* __restrict__ h,
                                                      const float* __restrict__ coef,
                                                      const float* __restrict__ W3,
                                                      float* __restrict__ sup3) {
    int lane = threadIdx.x & 63, wid = threadIdx.x >> 6;
    int gw = blockIdx.x * 4 + wid;
    if (gw >= NROWS) return;
    float2 w  = ((const float2*)W3)[lane];
    float2 sc = ((const float2*)coef)[lane];
    float2 sh = ((const float2*)(coef + 128))[lane];
    float2 v  = ((const float2*)h)[(size_t)gw * 64 + lane];
    v.x = fmaxf(v.x * sc.x + sh.x, 0.f);
    v.y = fmaxf(v.y * sc.y + sh.y, 0.f);
    float s = v.x * w.x + v.y * w.y;
    #pragma unroll
    for (int d = 32; d > 0; d >>= 1) s += __shfl_xor(s, d);
    if (lane == 0) sup3[gw] = s;
}

// out[b,n] = b3 + sum over CSR in-edges of sup3[b, src].
__global__ __launch_bounds__(256) void gather_out_kernel(const int* __restrict__ offsets,
                                                         const int* __restrict__ srcbuf,
                                                         const float* __restrict__ sup3,
                                                         const float* __restrict__ b3,
                                                         float* __restrict__ out) {
    int n = blockIdx.x * 256 + threadIdx.x;
    if (n >= N_NODES) return;
    int beg = offsets[n], end = offsets[n + 1];
    float s0 = 0.f, s1 = 0.f;
    for (int i = beg; i < end; ++i) {
        int r = srcbuf[i];
        s0 += sup3[r];
        s1 += sup3[N_NODES + r];
    }
    float b = b3[0];
    out[n] = s0 + b;
    out[N_NODES + n] = s1 + b;
}

// ---------------- launch ----------------

extern "C" void kernel_launch(void* const* d_in, const int* in_sizes, int n_in,
                              void* d_out, int out_size, void* d_ws, size_t ws_size,
                              hipStream_t stream) {
    const float* x      = (const float*)d_in[0];
    const int*   ei     = (const int*)d_in[1];
    const float* W1     = (const float*)d_in[2];
    // d_in[3] = b1: per-feature bias before BN cancels exactly (shifts mean identically)
    const float* W2     = (const float*)d_in[4];
    // d_in[5] = b2: same cancellation
    const float* W3     = (const float*)d_in[6];
    const float* b3     = (const float*)d_in[7];
    const float* gamma1 = (const float*)d_in[8];
    const float* beta1  = (const float*)d_in[9];
    const float* gamma2 = (const float*)d_in[10];
    const float* beta2  = (const float*)d_in[11];
    const int* rowp = ei;             // edge_index[0]
    const int* colp = ei + N_EDGES;   // edge_index[1]

    ushort_t* sup   = (ushort_t*)d_ws;              // 12.8M bf16 (25.6 MB)
    float* agg      = (float*)(sup + 12800000);     // 12.8M floats (51.2 MB)
    float* sup3     = agg + 12800000;               // 100k floats (16B-aligned region)
    ushort_t* wt    = (ushort_t*)(sup3 + 100000);   // 65536 ushorts: W1/W2 split planes
    float* stats    = (float*)(wt + 65536);         // 512 floats
    float* coef     = stats + 512;                  // 512 floats
    int*   cnt      = (int*)(coef + 512);           // 50000
    int*   offsets  = cnt + N_NODES;                // 50001
    int*   cursor   = offsets + N_NODES + 1;        // 50000
    int*   srcbuf   = cursor + N_NODES;             // 800000
    int*   partials = srcbuf + N_EDGES;             // 196
    float* out      = (float*)d_out;

    hipMemsetAsync(cnt, 0, N_NODES * sizeof(int), stream);
    hipMemsetAsync(stats, 0, 512 * sizeof(float), stream);

    // W split/transpose (once per launch) + CSR build
    wsplit_kernel     <<<128,         256, 0, stream>>>(W1, W2, wt);
    hist_kernel       <<<3125,        256, 0, stream>>>(colp, cnt);
    scan_partials_sum <<<SCAN_BLOCKS, 256, 0, stream>>>(cnt, partials);
    scan_partials_scan<<<1,           256, 0, stream>>>(partials, offsets);
    scan_final        <<<SCAN_BLOCKS, 256, 0, stream>>>(cnt, partials, offsets, cursor);
    bucket_kernel     <<<3125,        256, 0, stream>>>(rowp, colp, cursor, srcbuf);

    // layer 1: sup = x@W1 (split-bf16 MFMA -> bf16), agg = A·sup (fp32), stats
    gemm_mfma<false><<<1563,  256, 0, stream>>>(x, wt, nullptr, sup);
    aggregate_bf16  <<<12500, 256, 0, stream>>>(sup, offsets, srcbuf, agg);
    bn_stats_kernel <<<512,   256, 0, stream>>>(agg, stats);
    bn_coef_kernel  <<<1,     128, 0, stream>>>(stats, gamma1, beta1, coef);

    // layer 2: sup = relu(bn(agg))@W2 (BN fused into staging), agg = A·sup, stats
    gemm_mfma<true> <<<1563,  256, 0, stream>>>(agg, wt + 32768, coef, sup);
    aggregate_bf16  <<<12500, 256, 0, stream>>>(sup, offsets, srcbuf, agg);
    bn_stats_kernel <<<512,   256, 0, stream>>>(agg, stats + 256);
    bn_coef_kernel  <<<1,     128, 0, stream>>>(stats + 256, gamma2, beta2, coef + 256);

    // layer 3: sup3 = relu(bn(agg))@W3 (fused GEMV), out = A·sup3 + b3 (CSR gather)
    gemv_bn_kernel   <<<25000, 256, 0, stream>>>(agg, coef + 256, W3, sup3);
    gather_out_kernel<<<SCAN_BLOCKS, 256, 0, stream>>>(offsets, srcbuf, sup3, b3, out);
}